// Round 4
// baseline (362.693 us; speedup 1.0000x reference)
//
#include <hip/hip_runtime.h>
#include <hip/hip_cooperative_groups.h>

namespace cg = cooperative_groups;

// Problem constants (from reference setup_inputs)
#define B 8
#define C 64
#define H 152
#define W 272
#define HW (H * W)          // 41344
#define K 500
#define KP 512              // K padded to tile multiple
#define ALPHA 0.25f
#define PROB_MIN 1e-4f

#define NBLK 256            // 1 block/CU co-resident (coop launch safe)
#define NTHR 1024           // 16 waves per block

typedef __attribute__((ext_vector_type(8))) short short8;   // 8 bf16 (4 VGPRs)
typedef __attribute__((ext_vector_type(4))) float floatx4;  // 4 fp32 acc

// fp32 -> bf16 round-to-nearest-even
__device__ __forceinline__ unsigned short f32_to_bf16(float f) {
    union { float f; unsigned int u; } v; v.f = f;
    unsigned int r = v.u + 0x7FFFu + ((v.u >> 16) & 1u);
    return (unsigned short)(r >> 16);
}

__device__ __forceinline__ float focal_term(float x, int gi, int gj, int b,
                                            const int* __restrict__ tmask)
{
    if (gi >= K || gj >= K) return 0.0f;
    const float sim = 1.0f / (1.0f + __expf(-x));
    const int gt = (gi == gj) ? tmask[b * K + gi] : 0;
    float p = gt ? sim : 1.0f - sim;
    p = fminf(fmaxf(p, PROB_MIN), 1.0f);
    const float a = gt ? ALPHA : (1.0f - ALPHA);
    const float om = 1.0f - p;
    return a * om * om * (-__logf(p));
}

// ---------------------------------------------------------------------------
// Fused cooperative kernel.
// Phase 1: masked gather -> bf16 feats [B, KP, C] (round-2 mapping: lane =
//          channel -> coalesced feat writes; one cur + one pre element per
//          thread sharing the mask load). Zero-pads rows K..KP-1 and
//          zero-inits the scalar output (poisoned 0xAA before each replay).
// grid.sync() (device-scope fence), then
// Phase 2: per-wave 16x16 sim tiles via MFMA 16x16x32 bf16 (2 tiles/wave),
//          fused sigmoid+focal loss, block reduce, one atomicAdd per block.
// ---------------------------------------------------------------------------
__global__ __launch_bounds__(NTHR, 4) void fused_kernel(
    const float* __restrict__ cur_reid,
    const float* __restrict__ pre_reid,
    const int* __restrict__ cur_inds,
    const int* __restrict__ pre_inds,
    const int* __restrict__ cur_circ,
    const int* __restrict__ pre_circ,
    const int* __restrict__ tmask,
    unsigned short* __restrict__ curf,
    unsigned short* __restrict__ pref,
    float* __restrict__ out)
{
    const int t   = threadIdx.x;
    const int tid = blockIdx.x * NTHR + t;      // 0 .. 262143 = B*KP*C

    // ---- Phase 1: gather ----
    if (tid == 0) out[0] = 0.0f;
    {
        const int c = tid & 63;
        const int k = (tid >> 6) & (KP - 1);
        const int b = tid >> 15;
        unsigned short vc = 0, vp = 0;
        if (k < K) {
            const int bk = b * K + k;
            const int m  = tmask[bk];
            const int ic = m ? cur_inds[bk] : cur_circ[bk];
            const int ip = m ? pre_inds[bk] : pre_circ[bk];
            const size_t plane = ((size_t)(b * C + c)) * HW;
            vc = f32_to_bf16(cur_reid[plane + ic]);
            vp = f32_to_bf16(pre_reid[plane + ip]);
        }
        const size_t o = ((size_t)(b * KP + k)) * C + c;
        curf[o] = vc;   // coalesced (c contiguous across lanes)
        pref[o] = vp;
    }

    __threadfence();            // device-scope visibility across XCDs
    cg::this_grid().sync();

    // ---- Phase 2: 2 tiles per wave; 4096 waves cover 8192 tiles ----
    const int wave = t >> 6;
    const int lane = t & 63;
    const int m16  = lane & 15;
    const int quad = lane >> 4;
    const int w0   = blockIdx.x * (NTHR / 64) + wave;   // [0, 4096)

    float s = 0.f;
#pragma unroll
    for (int rep = 0; rep < 2; ++rep) {
        const int tile = w0 + rep * 4096;   // [0, 8192)
        const int b  = tile >> 10;          // 1024 tiles per batch
        const int ti = (tile >> 5) & 31;
        const int tj = tile & 31;

        const unsigned short* pa = curf + (((size_t)(b * KP + ti * 16 + m16)) * C + quad * 8);
        const unsigned short* pb = pref + (((size_t)(b * KP + tj * 16 + m16)) * C + quad * 8);
        const short8 a0 = *(const short8*)pa;
        const short8 a1 = *(const short8*)(pa + 32);
        const short8 b0 = *(const short8*)pb;
        const short8 b1 = *(const short8*)(pb + 32);

        floatx4 acc = {0.f, 0.f, 0.f, 0.f};
        acc = __builtin_amdgcn_mfma_f32_16x16x32_bf16(a0, b0, acc, 0, 0, 0);
        acc = __builtin_amdgcn_mfma_f32_16x16x32_bf16(a1, b1, acc, 0, 0, 0);

        // C/D layout: col = lane&15, row = quad*4 + reg   [measured m89/m91]
        const int gj = tj * 16 + m16;
#pragma unroll
        for (int r = 0; r < 4; ++r) {
            const int gi = ti * 16 + quad * 4 + r;
            s += focal_term(acc[r], gi, gj, b, tmask);
        }
    }

    // wave64 butterfly, then cross-wave via LDS, one atomic per block
    __shared__ float wsum[NTHR / 64];
#pragma unroll
    for (int o = 32; o > 0; o >>= 1) s += __shfl_down(s, o, 64);
    if (lane == 0) wsum[wave] = s;
    __syncthreads();
    if (t == 0) {
        float tot = 0.f;
#pragma unroll
        for (int w = 0; w < NTHR / 64; ++w) tot += wsum[w];
        atomicAdd(out, tot * (1.0f / ((float)B * (float)K * (float)K)));
    }
}

// ---------------------------------------------------------------------------
extern "C" void kernel_launch(void* const* d_in, const int* in_sizes, int n_in,
                              void* d_out, int out_size, void* d_ws, size_t ws_size,
                              hipStream_t stream)
{
    const float* cur_reid = (const float*)d_in[0];
    const float* pre_reid = (const float*)d_in[1];
    const int*   cur_inds = (const int*)d_in[2];
    const int*   pre_inds = (const int*)d_in[3];
    const int*   cur_circ = (const int*)d_in[4];
    const int*   pre_circ = (const int*)d_in[5];
    const int*   tmask    = (const int*)d_in[6];
    float*       out      = (float*)d_out;

    unsigned short* curf = (unsigned short*)d_ws;            // B*KP*C bf16 = 512 KB
    unsigned short* pref = curf + (size_t)B * KP * C;        // another 512 KB

    void* args[] = {
        (void*)&cur_reid, (void*)&pre_reid,
        (void*)&cur_inds, (void*)&pre_inds,
        (void*)&cur_circ, (void*)&pre_circ,
        (void*)&tmask, (void*)&curf, (void*)&pref, (void*)&out
    };
    hipLaunchCooperativeKernel((const void*)fused_kernel,
                               dim3(NBLK), dim3(NTHR), args, 0, stream);
}

// Round 5
// 176.581 us; speedup vs baseline: 2.0540x; 2.0540x over previous
//
#include <hip/hip_runtime.h>

// Problem constants (from reference setup_inputs)
#define B 8
#define C 64
#define H 152
#define W 272
#define HW (H * W)          // 41344
#define K 500
#define KP 512              // K padded to tile multiple
#define ALPHA 0.25f
#define PROB_MIN 1e-4f

// NOTE (round-4 lesson): a fused cooperative kernel with cg::grid().sync()
// cost ~198 us by itself -- the grid barrier on this 8-XCD part is O(100 us),
// vastly more than the ~3 us dispatch gap it saves. Two dispatches it is.

typedef __attribute__((ext_vector_type(8))) short short8;   // 8 bf16 (4 VGPRs)
typedef __attribute__((ext_vector_type(4))) float floatx4;  // 4 fp32 acc

// fp32 -> bf16 round-to-nearest-even
__device__ __forceinline__ unsigned short f32_to_bf16(float f) {
    union { float f; unsigned int u; } v; v.f = f;
    unsigned int r = v.u + 0x7FFFu + ((v.u >> 16) & 1u);
    return (unsigned short)(r >> 16);
}

// ---------------------------------------------------------------------------
// Kernel 1: masked gather -> bf16 feats [B, KP, C]; zero-pads rows K..KP-1.
// One block per (b,k): threads 0..63 gather cur channels, 64..127 pre.
// Inputs are L3-warm (restored immediately before), so this is latency/L3
// bound (~6 us); plenty of waves (4096 blocks) hide it.
// Also zero-initializes the scalar output (poisoned 0xAA before replay).
// ---------------------------------------------------------------------------
__global__ __launch_bounds__(128) void gather_kernel(
    const float* __restrict__ cur_reid,
    const float* __restrict__ pre_reid,
    const int* __restrict__ cur_inds,
    const int* __restrict__ pre_inds,
    const int* __restrict__ cur_circ,
    const int* __restrict__ pre_circ,
    const int* __restrict__ tmask,
    unsigned short* __restrict__ curf,
    unsigned short* __restrict__ pref,
    float* __restrict__ out)
{
    const int bk = blockIdx.x;          // 0 .. B*KP-1
    const int t  = threadIdx.x;         // 0 .. 127
    if (bk == 0 && t == 0) out[0] = 0.0f;  // before loss kernel (stream order)

    const int b = bk >> 9;              // /KP
    const int k = bk & (KP - 1);

    if (k >= K) {                       // padding rows -> zero
        if (t < C)      curf[(size_t)bk * C + t] = 0;
        else            pref[(size_t)bk * C + (t - C)] = 0;
        return;
    }

    const int bk_in = b * K + k;        // index into [B,K] arrays
    const int m = tmask[bk_in];
    if (t < C) {
        const int idx = m ? cur_inds[bk_in] : cur_circ[bk_in];
        const float v = cur_reid[((size_t)(b * C + t)) * HW + idx];
        curf[(size_t)bk * C + t] = f32_to_bf16(v);
    } else {
        const int c = t - C;
        const int idx = m ? pre_inds[bk_in] : pre_circ[bk_in];
        const float v = pre_reid[((size_t)(b * C + c)) * HW + idx];
        pref[(size_t)bk * C + c] = f32_to_bf16(v);
    }
}

// ---------------------------------------------------------------------------
// Kernel 2: per-wave 16x16 tile of sim via MFMA 16x16x32 bf16 (2 MFMAs, K=64),
// fragments loaded directly from global (feat fits in L2), fused sigmoid +
// focal loss + block reduce + one atomicAdd per block.
// ---------------------------------------------------------------------------
__device__ __forceinline__ float focal_term(float x, int gi, int gj, int b,
                                            const int* __restrict__ tmask)
{
    if (gi >= K || gj >= K) return 0.0f;
    const float sim = 1.0f / (1.0f + __expf(-x));
    const int gt = (gi == gj) ? tmask[b * K + gi] : 0;
    float p = gt ? sim : 1.0f - sim;
    p = fminf(fmaxf(p, PROB_MIN), 1.0f);
    const float a = gt ? ALPHA : (1.0f - ALPHA);
    const float om = 1.0f - p;
    return a * om * om * (-__logf(p));
}

#define LOSS_THREADS 1024   // 16 waves per block -> 16 tiles per block

__global__ __launch_bounds__(LOSS_THREADS) void loss_kernel(
    const unsigned short* __restrict__ curf,
    const unsigned short* __restrict__ pref,
    const int* __restrict__ tmask,
    float* __restrict__ out)
{
    __shared__ float wsum[LOSS_THREADS / 64];

    const int t    = threadIdx.x;
    const int wave = t >> 6;
    const int lane = t & 63;

    // Flat tile id -> (b, ti, tj); tiles: 32 x 32 per batch, 8 batches = 8192.
    const int tile = blockIdx.x * (LOSS_THREADS / 64) + wave;
    const int b    = tile >> 10;
    const int rem  = tile & 1023;
    const int ti   = rem >> 5;
    const int tj   = rem & 31;

    const int m16  = lane & 15;   // A-row / B-row (=sim col) within tile
    const int quad = lane >> 4;   // 0..3

    // A frag: curf[b][ti*16 + m16][quad*8 + (0..7)]  (+32 for second MFMA)
    const unsigned short* pa = curf + (((size_t)(b * KP + ti * 16 + m16)) * C + quad * 8);
    const unsigned short* pb = pref + (((size_t)(b * KP + tj * 16 + m16)) * C + quad * 8);
    const short8 a0 = *(const short8*)pa;
    const short8 a1 = *(const short8*)(pa + 32);
    const short8 b0 = *(const short8*)pb;
    const short8 b1 = *(const short8*)(pb + 32);

    floatx4 acc = {0.f, 0.f, 0.f, 0.f};
    acc = __builtin_amdgcn_mfma_f32_16x16x32_bf16(a0, b0, acc, 0, 0, 0);
    acc = __builtin_amdgcn_mfma_f32_16x16x32_bf16(a1, b1, acc, 0, 0, 0);

    // C/D layout: col = lane&15, row = quad*4 + reg   [measured m89/m91]
    const int gj = tj * 16 + m16;
    float s = 0.f;
#pragma unroll
    for (int r = 0; r < 4; ++r) {
        const int gi = ti * 16 + quad * 4 + r;
        s += focal_term(acc[r], gi, gj, b, tmask);
    }

    // wave64 butterfly, then cross-wave via LDS, one atomic per block
#pragma unroll
    for (int o = 32; o > 0; o >>= 1) s += __shfl_down(s, o, 64);
    if (lane == 0) wsum[wave] = s;
    __syncthreads();
    if (t == 0) {
        float tot = 0.f;
#pragma unroll
        for (int w = 0; w < LOSS_THREADS / 64; ++w) tot += wsum[w];
        atomicAdd(out, tot * (1.0f / ((float)B * (float)K * (float)K)));
    }
}

// ---------------------------------------------------------------------------
extern "C" void kernel_launch(void* const* d_in, const int* in_sizes, int n_in,
                              void* d_out, int out_size, void* d_ws, size_t ws_size,
                              hipStream_t stream)
{
    const float* cur_reid = (const float*)d_in[0];
    const float* pre_reid = (const float*)d_in[1];
    const int*   cur_inds = (const int*)d_in[2];
    const int*   pre_inds = (const int*)d_in[3];
    const int*   cur_circ = (const int*)d_in[4];
    const int*   pre_circ = (const int*)d_in[5];
    const int*   tmask    = (const int*)d_in[6];
    float*       out      = (float*)d_out;

    unsigned short* curf = (unsigned short*)d_ws;            // B*KP*C bf16 = 512 KB
    unsigned short* pref = curf + (size_t)B * KP * C;        // another 512 KB

    gather_kernel<<<B * KP, 128, 0, stream>>>(
        cur_reid, pre_reid, cur_inds, pre_inds, cur_circ, pre_circ, tmask,
        curf, pref, out);

    // 8192 tiles (32x32x8) / 16 waves per block = 512 blocks
    loss_kernel<<<512, LOSS_THREADS, 0, stream>>>(curf, pref, tmask, out);
}